// Round 9
// baseline (22.404 us; speedup 1.0000x reference)
//
#include <hip/hip_runtime.h>

// Problem constants (from reference setup_inputs)
#define BB   64
#define NQ   900
#define NC   256
#define NT   128

#define RPW  4    // rows per wave per piece (one per 16-lane group)
#define RPB  16   // rows per piece (4 waves)
#define NBX  29   // ceil(900 / 32) blocks in q; each block = 2 pieces = 32 rows

typedef float f32x2 __attribute__((ext_vector_type(2)));
typedef const __attribute__((address_space(1))) void gas_t;
typedef __attribute__((address_space(3))) void las_t;

// DPP butterfly add across a 16-lane group (VALU pipe, no LDS)
template<int CTRL>
__device__ __forceinline__ float dpp_add(float x) {
    int y = __builtin_amdgcn_update_dpp(0, __float_as_int(x), CTRL, 0xF, 0xF, true);
    return x + __int_as_float(y);
}

__device__ __forceinline__ float lane_bcast(float x, int l) {
    return __int_as_float(__builtin_amdgcn_readlane(__float_as_int(x), l));
}

__global__ __launch_bounds__(256, 4) void matcher_kernel(
    const float* __restrict__ logits,   // [B, NQ, 256]
    const float* __restrict__ pboxes,   // [B, NQ, 4] cxcywh
    const int*   __restrict__ tlabels,  // [B, 128]
    const float* __restrict__ tboxes,   // [B, 128, 4] cxcywh
    float* __restrict__ out)            // [B, NQ, 128]
{
    constexpr float W_BBOX = 5.0f, W_GIOU = 2.0f, EPS = 1e-6f;

    __shared__ __align__(16) float raw [RPB][NC];  // piece 0: reg->ds_write path
    __shared__ __align__(16) float raw2[RPB][NC];  // piece 1: global_load_lds DMA

    const int wave = threadIdx.x >> 6;
    const int lane = threadIdx.x & 63;
    const int g    = lane >> 4;
    const int j    = lane & 15;
    const int b    = blockIdx.y;
    const int wr0  = wave * RPW;
    const int q0a  = blockIdx.x * (2 * RPB) + wr0;        // piece-0 rows
    const int q0b  = q0a + RPB;                           // piece-1 rows

    const size_t rowbase = (size_t)b * NQ;

    // ---- 1) DMA piece-1 logits to LDS FIRST (oldest in vmcnt queue, 0 VGPR) ----
    #pragma unroll
    for (int k = 0; k < RPW; ++k) {
        int q = q0b + k; q = q < NQ - 1 ? q : NQ - 1;     // tail clamp
        const float* src = logits + (rowbase + q) * NC + lane * 4;
        __builtin_amdgcn_global_load_lds((gas_t*)src, (las_t*)&raw2[wr0 + k][0],
                                         16, 0, 0);
    }

    // ---- 2) piece-0 register loads (R7 skeleton, compiler-scheduled) ----
    int qg = q0a + g; qg = qg < NQ - 1 ? qg : NQ - 1;
    const float* lrow = logits + (rowbase + qg) * NC + j * 4;
    const float4 v0 = *reinterpret_cast<const float4*>(lrow);
    const float4 v1 = *reinterpret_cast<const float4*>(lrow + 64);
    const float4 v2 = *reinterpret_cast<const float4*>(lrow + 128);
    const float4 v3 = *reinterpret_cast<const float4*>(lrow + 192);

    float4 pba[RPW], pbb[RPW];
    #pragma unroll
    for (int r = 0; r < RPW; ++r) {
        int qa = q0a + r; qa = qa < NQ - 1 ? qa : NQ - 1;
        int qb = q0b + r; qb = qb < NQ - 1 ? qb : NQ - 1;
        pba[r] = *reinterpret_cast<const float4*>(pboxes + (rowbase + qa) * 4);
        pbb[r] = *reinterpret_cast<const float4*>(pboxes + (rowbase + qb) * 4);
    }

    const int t0 = lane * 2;
    const int2   lbl = *reinterpret_cast<const int2*>(tlabels + b * NT + t0);
    const float4 ta  = *reinterpret_cast<const float4*>(tboxes + ((size_t)b * NT + t0) * 4);
    const float4 tbv = *reinterpret_cast<const float4*>(tboxes + ((size_t)b * NT + t0 + 1) * 4);

    // ---- per-lane target constants (shared by both pieces) ----
    const float ax1 = ta.x - 0.5f * ta.z, ay1 = ta.y - 0.5f * ta.w;
    const float ax2 = ta.x + 0.5f * ta.z, ay2 = ta.y + 0.5f * ta.w;
    const float aarea = fmaxf(ax2 - ax1, 0.0f) * fmaxf(ay2 - ay1, 0.0f);
    const float bx1 = tbv.x - 0.5f * tbv.z, by1 = tbv.y - 0.5f * tbv.w;
    const float bx2 = tbv.x + 0.5f * tbv.z, by2 = tbv.y + 0.5f * tbv.w;
    const float barea = fmaxf(bx2 - bx1, 0.0f) * fmaxf(by2 - by1, 0.0f);

    // cost for one (row-box pb, its softmax inv, this lane's 2 targets) -> store
    auto cost_store = [&](const float4& pb, float p0e, float p1e, float invs, int q) {
        const float p0 = p0e * invs;
        const float p1 = p1e * invs;

        const float px1 = pb.x - 0.5f * pb.z, py1 = pb.y - 0.5f * pb.w;
        const float px2 = pb.x + 0.5f * pb.z, py2 = pb.y + 0.5f * pb.w;
        const float parea = fmaxf(px2 - px1, 0.0f) * fmaxf(py2 - py1, 0.0f);

        const float l1a = fabsf(pb.x - ta.x) + fabsf(pb.y - ta.y)
                        + fabsf(pb.z - ta.z) + fabsf(pb.w - ta.w);
        const float ia  = fmaxf(fminf(px2, ax2) - fmaxf(px1, ax1), 0.0f)
                        * fmaxf(fminf(py2, ay2) - fmaxf(py1, ay1), 0.0f);
        const float ua  = parea + aarea - ia + EPS;
        const float ea  = fmaxf(fmaxf(px2, ax2) - fminf(px1, ax1), 0.0f)
                        * fmaxf(fmaxf(py2, ay2) - fminf(py1, ay1), 0.0f) + EPS;
        const float gioua = ia * __builtin_amdgcn_rcpf(ua)
                          - (ea - ua) * __builtin_amdgcn_rcpf(ea);
        const float c0 = -p0 + W_BBOX * l1a - W_GIOU * gioua;

        const float l1b = fabsf(pb.x - tbv.x) + fabsf(pb.y - tbv.y)
                        + fabsf(pb.z - tbv.z) + fabsf(pb.w - tbv.w);
        const float ib  = fmaxf(fminf(px2, bx2) - fmaxf(px1, bx1), 0.0f)
                        * fmaxf(fminf(py2, by2) - fmaxf(py1, by1), 0.0f);
        const float ub  = parea + barea - ib + EPS;
        const float eb  = fmaxf(fmaxf(px2, bx2) - fminf(px1, bx1), 0.0f)
                        * fmaxf(fmaxf(py2, by2) - fminf(py1, by1), 0.0f) + EPS;
        const float gioub = ib * __builtin_amdgcn_rcpf(ub)
                          - (eb - ub) * __builtin_amdgcn_rcpf(eb);
        const float c1 = -p1 + W_BBOX * l1b - W_GIOU * gioub;

        f32x2 cc; cc.x = c0; cc.y = c1;
        __builtin_nontemporal_store(cc,
            reinterpret_cast<f32x2*>(out + (rowbase + q) * NT + t0));
    };

    // ================= piece 0 (registers, as R7) =================
    {
        float* srow = &raw[wr0 + g][j * 4];
        *reinterpret_cast<float4*>(srow)       = v0;
        *reinterpret_cast<float4*>(srow + 64)  = v1;
        *reinterpret_cast<float4*>(srow + 128) = v2;
        *reinterpret_cast<float4*>(srow + 192) = v3;

        float ga[RPW], gb[RPW];
        #pragma unroll
        for (int r = 0; r < RPW; ++r) {
            ga[r] = raw[wr0 + r][lbl.x];
            gb[r] = raw[wr0 + r][lbl.y];
        }

        float s = (((__expf(v0.x) + __expf(v0.y)) + (__expf(v0.z) + __expf(v0.w)))
                +  ((__expf(v1.x) + __expf(v1.y)) + (__expf(v1.z) + __expf(v1.w))))
                + (((__expf(v2.x) + __expf(v2.y)) + (__expf(v2.z) + __expf(v2.w)))
                +  ((__expf(v3.x) + __expf(v3.y)) + (__expf(v3.z) + __expf(v3.w))));
        s = dpp_add<0xB1>(s); s = dpp_add<0x4E>(s);
        s = dpp_add<0x141>(s); s = dpp_add<0x140>(s);

        const float inv[RPW] = {
            __builtin_amdgcn_rcpf(lane_bcast(s, 0)),
            __builtin_amdgcn_rcpf(lane_bcast(s, 16)),
            __builtin_amdgcn_rcpf(lane_bcast(s, 32)),
            __builtin_amdgcn_rcpf(lane_bcast(s, 48)) };

        if (q0a < NQ) {   // wave-uniform (rows q0a..q0a+3 same validity; NQ%4==0)
            #pragma unroll
            for (int r = 0; r < RPW; ++r)
                cost_store(pba[r], __expf(ga[r]), __expf(gb[r]), inv[r], q0a + r);
        }
    }

    // ---- DMA completion: allow only the 4 newest vmem ops (piece-0 stores) ----
    asm volatile("s_waitcnt vmcnt(4)" ::: "memory");
    __builtin_amdgcn_sched_barrier(0);

    // ================= piece 1 (from LDS) =================
    {
        float ga[RPW], gb[RPW];
        #pragma unroll
        for (int r = 0; r < RPW; ++r) {
            ga[r] = raw2[wr0 + r][lbl.x];
            gb[r] = raw2[wr0 + r][lbl.y];
        }

        const float* rr = &raw2[wr0 + g][j * 4];
        const float4 w0 = *reinterpret_cast<const float4*>(rr);
        const float4 w1 = *reinterpret_cast<const float4*>(rr + 64);
        const float4 w2 = *reinterpret_cast<const float4*>(rr + 128);
        const float4 w3 = *reinterpret_cast<const float4*>(rr + 192);

        float s = (((__expf(w0.x) + __expf(w0.y)) + (__expf(w0.z) + __expf(w0.w)))
                +  ((__expf(w1.x) + __expf(w1.y)) + (__expf(w1.z) + __expf(w1.w))))
                + (((__expf(w2.x) + __expf(w2.y)) + (__expf(w2.z) + __expf(w2.w)))
                +  ((__expf(w3.x) + __expf(w3.y)) + (__expf(w3.z) + __expf(w3.w))));
        s = dpp_add<0xB1>(s); s = dpp_add<0x4E>(s);
        s = dpp_add<0x141>(s); s = dpp_add<0x140>(s);

        const float inv[RPW] = {
            __builtin_amdgcn_rcpf(lane_bcast(s, 0)),
            __builtin_amdgcn_rcpf(lane_bcast(s, 16)),
            __builtin_amdgcn_rcpf(lane_bcast(s, 32)),
            __builtin_amdgcn_rcpf(lane_bcast(s, 48)) };

        if (q0b < NQ) {
            #pragma unroll
            for (int r = 0; r < RPW; ++r)
                cost_store(pbb[r], __expf(ga[r]), __expf(gb[r]), inv[r], q0b + r);
        }
    }
}

extern "C" void kernel_launch(void* const* d_in, const int* in_sizes, int n_in,
                              void* d_out, int out_size, void* d_ws, size_t ws_size,
                              hipStream_t stream) {
    const float* logits  = (const float*)d_in[0];
    const float* pboxes  = (const float*)d_in[1];
    const int*   tlabels = (const int*)d_in[2];
    const float* tboxes  = (const float*)d_in[3];
    float* out = (float*)d_out;

    dim3 grid(NBX, BB);
    matcher_kernel<<<grid, 256, 0, stream>>>(logits, pboxes, tlabels, tboxes, out);
}

// Round 10
// 21.249 us; speedup vs baseline: 1.0544x; 1.0544x over previous
//
#include <hip/hip_runtime.h>

// Problem constants (from reference setup_inputs)
#define BB   64
#define NQ   900
#define NC   256
#define NT   128

#define RPW  2    // rows per wave: one per 32-lane group
#define RPB  8    // rows per block (4 waves)
#define NBX  113  // ceil(900/8); last block rows 896..903 -> guarded

typedef float f32x2 __attribute__((ext_vector_type(2)));

// DPP butterfly add across a 16-lane group (VALU pipe, no LDS)
template<int CTRL>
__device__ __forceinline__ float dpp_add(float x) {
    int y = __builtin_amdgcn_update_dpp(0, __float_as_int(x), CTRL, 0xF, 0xF, true);
    return x + __int_as_float(y);
}

__device__ __forceinline__ float lane_bcast(float x, int l) {
    return __int_as_float(__builtin_amdgcn_readlane(__float_as_int(x), l));
}

// __launch_bounds__(256, 8): forces VGPR <= 64 -> 8 waves/SIMD = 32 waves/CU.
// TLP-doubling probe vs R7/R8's 4 waves/SIMD at identical traffic.
__global__ __launch_bounds__(256, 8) void matcher_kernel(
    const float* __restrict__ logits,   // [B, NQ, 256]
    const float* __restrict__ pboxes,   // [B, NQ, 4] cxcywh
    const int*   __restrict__ tlabels,  // [B, 128]
    const float* __restrict__ tboxes,   // [B, 128, 4] cxcywh
    float* __restrict__ out)            // [B, NQ, 128]
{
    constexpr float W_BBOX = 5.0f, W_GIOU = 2.0f, EPS = 1e-6f;

    __shared__ __align__(16) float raw[RPB][NC];   // RAW logits, 8 KB

    const int wave = threadIdx.x >> 6;
    const int lane = threadIdx.x & 63;
    const int h    = lane >> 5;         // which of the wave's 2 rows
    const int i    = lane & 31;
    const int b    = blockIdx.y;
    const int q0   = blockIdx.x * RPB + wave * RPW;
    if (q0 >= NQ) return;               // wave-uniform (block 112, waves 2-3)
    const int wr0  = wave * RPW;
    const size_t rowbase = (size_t)b * NQ;

    // ---- global loads up front ----
    int qg = q0 + h; qg = qg < NQ - 1 ? qg : NQ - 1;       // tail clamp (load only)
    const float* lrow = logits + (rowbase + qg) * NC + i * 4;
    const float4 v0 = *reinterpret_cast<const float4*>(lrow);
    const float4 v1 = *reinterpret_cast<const float4*>(lrow + 128);

    float4 pb[RPW];
    #pragma unroll
    for (int r = 0; r < RPW; ++r) {
        int q = q0 + r; q = q < NQ - 1 ? q : NQ - 1;
        pb[r] = *reinterpret_cast<const float4*>(pboxes + (rowbase + q) * 4);
    }

    const int t0 = lane * 2;
    const int2   lbl = *reinterpret_cast<const int2*>(tlabels + b * NT + t0);
    const float4 ta  = *reinterpret_cast<const float4*>(tboxes + ((size_t)b * NT + t0) * 4);
    const float4 tbv = *reinterpret_cast<const float4*>(tboxes + ((size_t)b * NT + t0 + 1) * 4);

    // ---- stash RAW logits to LDS (no exp on the write path) ----
    float* srow = &raw[wr0 + h][i * 4];
    *reinterpret_cast<float4*>(srow)       = v0;
    *reinterpret_cast<float4*>(srow + 128) = v1;

    // ---- label gathers of raw logits ----
    float ga[RPW], gb[RPW];
    #pragma unroll
    for (int r = 0; r < RPW; ++r) {
        ga[r] = raw[wr0 + r][lbl.x];
        gb[r] = raw[wr0 + r][lbl.y];
    }

    // ---- exp + tree + 4-step DPP (sum-of-16 per group) + readlane combine ----
    float s = ((__expf(v0.x) + __expf(v0.y)) + (__expf(v0.z) + __expf(v0.w)))
            + ((__expf(v1.x) + __expf(v1.y)) + (__expf(v1.z) + __expf(v1.w)));
    s = dpp_add<0xB1>(s);   // quad_perm xor1
    s = dpp_add<0x4E>(s);   // quad_perm xor2
    s = dpp_add<0x141>(s);  // row_half_mirror (sum of 8)
    s = dpp_add<0x140>(s);  // row_mirror      (sum of 16)

    // row h sum = lanes [h*32, h*32+16) partials; combine via SGPR adds
    const float inv[RPW] = {
        __builtin_amdgcn_rcpf(lane_bcast(s, 0)  + lane_bcast(s, 16)),
        __builtin_amdgcn_rcpf(lane_bcast(s, 32) + lane_bcast(s, 48)) };

    // ---- per row: prob at gather time, box costs (targets recomputed), store ----
    #pragma unroll
    for (int r = 0; r < RPW; ++r) {
        if (q0 + r >= NQ) break;        // wave-uniform tail guard

        const float p0 = __expf(ga[r]) * inv[r];
        const float p1 = __expf(gb[r]) * inv[r];

        const float px1 = pb[r].x - 0.5f * pb[r].z, py1 = pb[r].y - 0.5f * pb[r].w;
        const float px2 = pb[r].x + 0.5f * pb[r].z, py2 = pb[r].y + 0.5f * pb[r].w;
        const float parea = fmaxf(px2 - px1, 0.0f) * fmaxf(py2 - py1, 0.0f);

        // target A (corners/area recomputed -> fewer live VGPRs)
        const float ax1 = ta.x - 0.5f * ta.z, ay1 = ta.y - 0.5f * ta.w;
        const float ax2 = ta.x + 0.5f * ta.z, ay2 = ta.y + 0.5f * ta.w;
        const float aarea = fmaxf(ax2 - ax1, 0.0f) * fmaxf(ay2 - ay1, 0.0f);
        const float l1a = fabsf(pb[r].x - ta.x) + fabsf(pb[r].y - ta.y)
                        + fabsf(pb[r].z - ta.z) + fabsf(pb[r].w - ta.w);
        const float ia  = fmaxf(fminf(px2, ax2) - fmaxf(px1, ax1), 0.0f)
                        * fmaxf(fminf(py2, ay2) - fmaxf(py1, ay1), 0.0f);
        const float ua  = parea + aarea - ia + EPS;
        const float ea  = fmaxf(fmaxf(px2, ax2) - fminf(px1, ax1), 0.0f)
                        * fmaxf(fmaxf(py2, ay2) - fminf(py1, ay1), 0.0f) + EPS;
        const float gioua = ia * __builtin_amdgcn_rcpf(ua)
                          - (ea - ua) * __builtin_amdgcn_rcpf(ea);
        const float c0 = -p0 + W_BBOX * l1a - W_GIOU * gioua;

        // target B
        const float bx1 = tbv.x - 0.5f * tbv.z, by1 = tbv.y - 0.5f * tbv.w;
        const float bx2 = tbv.x + 0.5f * tbv.z, by2 = tbv.y + 0.5f * tbv.w;
        const float barea = fmaxf(bx2 - bx1, 0.0f) * fmaxf(by2 - by1, 0.0f);
        const float l1b = fabsf(pb[r].x - tbv.x) + fabsf(pb[r].y - tbv.y)
                        + fabsf(pb[r].z - tbv.z) + fabsf(pb[r].w - tbv.w);
        const float ib  = fmaxf(fminf(px2, bx2) - fmaxf(px1, bx1), 0.0f)
                        * fmaxf(fminf(py2, by2) - fmaxf(py1, by1), 0.0f);
        const float ub  = parea + barea - ib + EPS;
        const float eb  = fmaxf(fmaxf(px2, bx2) - fminf(px1, bx1), 0.0f)
                        * fmaxf(fmaxf(py2, by2) - fminf(py1, by1), 0.0f) + EPS;
        const float gioub = ib * __builtin_amdgcn_rcpf(ub)
                          - (eb - ub) * __builtin_amdgcn_rcpf(eb);
        const float c1 = -p1 + W_BBOX * l1b - W_GIOU * gioub;

        f32x2 cc; cc.x = c0; cc.y = c1;
        __builtin_nontemporal_store(cc,
            reinterpret_cast<f32x2*>(out + (rowbase + q0 + r) * NT + t0));
    }
}

extern "C" void kernel_launch(void* const* d_in, const int* in_sizes, int n_in,
                              void* d_out, int out_size, void* d_ws, size_t ws_size,
                              hipStream_t stream) {
    const float* logits  = (const float*)d_in[0];
    const float* pboxes  = (const float*)d_in[1];
    const int*   tlabels = (const int*)d_in[2];
    const float* tboxes  = (const float*)d_in[3];
    float* out = (float*)d_out;

    dim3 grid(NBX, BB);
    matcher_kernel<<<grid, 256, 0, stream>>>(logits, pboxes, tlabels, tboxes, out);
}